// Round 2
// 225.733 us; speedup vs baseline: 1.1995x; 1.1995x over previous
//
#include <hip/hip_runtime.h>
#include <hip/hip_bf16.h>

#define NE 16
#define NN 4
#define DDIM 128
#define KD 64
#define HD 45

typedef _Float16 half8 __attribute__((ext_vector_type(8)));
typedef float floatx4 __attribute__((ext_vector_type(4)));

// ws byte offsets (static region)
#define OFF_FLAG_B 0
#define OFF_B1_B   64       // fp32 [9][48] (pad cols 45..47 = 0)
#define OFF_XT_B   1792     // fp32 [128]
#define OFF_H0_B   2304     // f16 [2][64]
#define OFF_YW_B   2560     // f16 [4][64]
#define OFF_W1_B   3072     // f16 frag [9][3nt][512]
#define OFF_W2_B   30720    // f16 frag [9][4nt][2kt][512] (rows 45..63 zero)
#define OFF_GW_B   104448   // f16 frag [9][8nt][2kt][512]
#define OFF_HW_B   251904   // f16 frag [4][4nt][4kt][512]
#define OFF_RL_B   317440   // int rl[3][16][8]: local_e | (s<<16)

__device__ __forceinline__ float ldf(const void* p, long i, int f32) {
    if (f32) return ((const float*)p)[i];
    unsigned int u = ((unsigned int)((const unsigned short*)p)[i]) << 16;
    return __uint_as_float(u);
}

__global__ void detect_kernel(const unsigned short* rs16, char* wsB) {
    __shared__ int bad;
    if (threadIdx.x == 0) bad = 0;
    __syncthreads();
    for (int i = threadIdx.x; i < 2048; i += 256) {
        unsigned int u = ((unsigned int)rs16[i]) << 16;
        float v = __uint_as_float(u);
        if (!(fabsf(v) < 1e6f)) atomicOr(&bad, 1);
    }
    __syncthreads();
    if (threadIdx.x == 0) *(int*)(wsB + OFF_FLAG_B) = bad ? 1 : 0;
}

__global__ void prep_kernel(const void* w1, const void* b1, const void* w2, const void* h0,
                            const void* hW, const void* gW, const void* Yw, const void* Xt,
                            char* wsB) {
    const int f32 = *(const int*)(wsB + OFF_FLAG_B);
    int i = blockIdx.x * 256 + threadIdx.x;
    _Float16* W1F = (_Float16*)(wsB + OFF_W1_B);
    _Float16* W2F = (_Float16*)(wsB + OFF_W2_B);
    _Float16* GWF = (_Float16*)(wsB + OFF_GW_B);
    _Float16* HWF = (_Float16*)(wsB + OFF_HW_B);
    float*    B1  = (float*)(wsB + OFF_B1_B);
    float*    XT  = (float*)(wsB + OFF_XT_B);
    _Float16* H0F = (_Float16*)(wsB + OFF_H0_B);
    _Float16* YWF = (_Float16*)(wsB + OFF_YW_B);

    if (i < 13824) {
        int lj = i / 1536, rem = i % 1536;
        int nt = rem >> 9, lane = (rem & 511) >> 3, e = rem & 7;
        int row = ((lane >> 4) << 3) + e;
        int col = (nt << 4) + (lane & 15);
        W1F[i] = (_Float16)((col < 45) ? ldf(w1, lj * 1440 + row * 45 + col, f32) : 0.f);
    }
    if (i < 36864) {
        int lj = i / 4096, rem = i & 4095;
        int nt = rem >> 10, kt = (rem >> 9) & 1, lane = (rem & 511) >> 3, e = rem & 7;
        int row = (kt << 5) + ((lane >> 4) << 3) + e;
        int col = (nt << 4) + (lane & 15);
        W2F[i] = (_Float16)((row < 45) ? ldf(w2, lj * 2880 + row * 64 + col, f32) : 0.f);
    }
    if (i < 73728) {
        int lj = i >> 13, rem = i & 8191;
        int nt = rem >> 10, kt = (rem >> 9) & 1, lane = (rem & 511) >> 3, e = rem & 7;
        int row = (kt << 5) + ((lane >> 4) << 3) + e;
        int col = (nt << 4) + (lane & 15);
        GWF[i] = (_Float16)ldf(gW, lj * 8192 + row * 128 + col, f32);
    }
    if (i < 32768) {
        int lj = i >> 13, rem = i & 8191;
        int nt = rem >> 11, kt = (rem >> 9) & 3, lane = (rem & 511) >> 3, e = rem & 7;
        int row = (kt << 5) + ((lane >> 4) << 3) + e;
        int col = (nt << 4) + (lane & 15);
        HWF[i] = (_Float16)ldf(hW, lj * 8192 + row * 64 + col, f32);
    }
    if (i < 432) { int lj = i / 48, n = i % 48; B1[i] = (n < 45) ? ldf(b1, lj * 45 + n, f32) : 0.f; }
    if (i < 128) XT[i] = ldf(Xt, i, f32);
    if (i < 128) H0F[i] = (_Float16)ldf(h0, i, f32);
    if (i < 256) YWF[i] = (_Float16)ldf(Yw, i, f32);
}

// rl lists store CLASS-LOCAL edge index (we lives per-class in LDS)
__global__ void rlbuild_kernel(const int* __restrict__ same_s, const int* __restrict__ same_r,
                               const int* __restrict__ anti_s, const int* __restrict__ anti_r,
                               const int* __restrict__ ne_s,   const int* __restrict__ ne_r,
                               char* wsB) {
    int lane = threadIdx.x;
    if (lane >= 48) return;
    int j = lane >> 4, r = lane & 15;
    int* rl = (int*)(wsB + OFF_RL_B) + lane * 8;
    int cnt  = (j == 0) ? 112 : ((j == 1) ? 128 : 64);
    const int* rr = (j == 0) ? same_r : ((j == 1) ? anti_r : ne_r);
    const int* ss = (j == 0) ? same_s : ((j == 1) ? anti_s : ne_s);
    int n = 0;
    for (int i = 0; i < cnt && n < 8; ++i)
        if (rr[i] == r) { rl[n++] = i | (ss[i] << 16); }
    for (; n < 8; ++n) rl[n] = 0;
}

// ---- distance + algebraic featurization for one 16-edge tile ----
// f_c(d) = d^2 * exp(A_c*d^2 + B_c*d + C_c),
// A = -1/s^2, B = 2*mu/s^2 - 1, C = -mu^2/s^2  (identical math to
// d^2*exp(-d)*exp(-((d-mu)/s)^2), rearranged to 2 FMA + 1 exp per channel)
__device__ __forceinline__ half8 feat_tile(
    const void* __restrict__ rs, const void* __restrict__ coords,
    int b, int lm, int f32, int tloc, int cls,
    const int* __restrict__ S, const int* __restrict__ R,
    const float* __restrict__ A0, const float* __restrict__ B0, const float* __restrict__ C0)
{
    int le = tloc * 16 + lm;
    int s = S[le], r = R[le];
    long rb = ((long)b * NE + r) * 3;
    float bx = ldf(rs, rb + 0, f32), by = ldf(rs, rb + 1, f32), bz = ldf(rs, rb + 2, f32);
    float ax, ay, az;
    if (cls < 2) {
        long sb = ((long)b * NE + s) * 3;
        ax = ldf(rs, sb + 0, f32); ay = ldf(rs, sb + 1, f32); az = ldf(rs, sb + 2, f32);
    } else {
        ax = ldf(coords, s * 3 + 0, f32); ay = ldf(coords, s * 3 + 1, f32); az = ldf(coords, s * 3 + 2, f32);
    }
    float dx = ax - bx, dy = ay - by, dz = az - bz;
    float d = sqrtf(dx * dx + dy * dy + dz * dz);
    float d2 = d * d;
    half8 a;
    #pragma unroll
    for (int ii = 0; ii < 8; ++ii) {
        float E = fmaf(A0[ii], d2, fmaf(B0[ii], d, C0[ii]));
        a[ii] = (_Float16)(d2 * __expf(E));
    }
    return a;
}

// ---- one 16-edge tile of the w-MLP: feat -> silu hidden -> we[16][64] to LDS ----
__device__ __forceinline__ void we_tile(
    half8 fa, int lj, int tt,
    const char* __restrict__ wsB, _Float16* __restrict__ hid,
    _Float16* __restrict__ weS, int lane, int qd, int lm)
{
    const half8* W1F_lj = (const half8*)(wsB + OFF_W1_B) + lj * 192;
    half8 w0 = W1F_lj[lane], w1v = W1F_lj[64 + lane], w2v = W1F_lj[128 + lane];
    const float* B1 = (const float*)(wsB + OFF_B1_B) + lj * 48;
    float bi0 = B1[lm], bi1 = B1[16 + lm], bi2 = B1[32 + lm];
    floatx4 c0 = {0.f,0.f,0.f,0.f}, c1 = c0, c2 = c0;
    c0 = __builtin_amdgcn_mfma_f32_16x16x32_f16(fa, w0,  c0, 0, 0, 0);
    c1 = __builtin_amdgcn_mfma_f32_16x16x32_f16(fa, w1v, c1, 0, 0, 0);
    c2 = __builtin_amdgcn_mfma_f32_16x16x32_f16(fa, w2v, c2, 0, 0, 0);
    #pragma unroll
    for (int rr = 0; rr < 4; ++rr) {
        int row = qd * 4 + rr;
        float v0 = c0[rr] + bi0, v1 = c1[rr] + bi1, v2 = c2[rr] + bi2;
        v0 = v0 * __builtin_amdgcn_rcpf(1.f + __expf(-v0));
        v1 = v1 * __builtin_amdgcn_rcpf(1.f + __expf(-v1));
        v2 = v2 * __builtin_amdgcn_rcpf(1.f + __expf(-v2));
        hid[row * 64 + lm]      = (_Float16)v0;
        hid[row * 64 + 16 + lm] = (_Float16)v1;
        hid[row * 64 + 32 + lm] = (_Float16)v2;
    }
    half8 a0 = *(const half8*)(hid + lm * 64 + qd * 8);
    half8 a1 = *(const half8*)(hid + lm * 64 + 32 + qd * 8);
    const half8* W2F_lj = (const half8*)(wsB + OFF_W2_B) + lj * 512;
    _Float16* wrow = weS + tt * 1024;
    #pragma unroll
    for (int nt = 0; nt < 4; ++nt) {
        half8 bk0 = W2F_lj[nt * 128 + lane], bk1 = W2F_lj[nt * 128 + 64 + lane];
        floatx4 acc = {0.f,0.f,0.f,0.f};
        acc = __builtin_amdgcn_mfma_f32_16x16x32_f16(a0, bk0, acc, 0, 0, 0);
        acc = __builtin_amdgcn_mfma_f32_16x16x32_f16(a1, bk1, acc, 0, 0, 0);
        #pragma unroll
        for (int rr = 0; rr < 4; ++rr)
            wrow[(qd * 4 + rr) * 64 + nt * 16 + lm] = (_Float16)acc[rr];
    }
}

// ---- scatter (rl gather-sum) -> z, then z @ gW accumulated into elec regs ----
// entry: weS for class J ready (caller synced). contains 2 internal barriers.
template<int J, int CNT>
__device__ __forceinline__ void scatter_zf_gmm(
    int L, int wv, int lane, int qd, int lm,
    const _Float16* __restrict__ weS, const _Float16* __restrict__ hxrow,
    const int* __restrict__ rlS, float* __restrict__ zS,
    const half8* __restrict__ GWF, floatx4 (&eacc)[2])
{
    #pragma unroll
    for (int rr4 = 0; rr4 < 4; ++rr4) {
        const int r = wv * 4 + rr4;
        const int* rlj = rlS + (J * 16 + r) * 8;
        float acc = 0.f;
        #pragma unroll
        for (int i = 0; i < CNT; ++i) {
            int pk = rlj[i];
            int e = pk & 0xFFFF, s = pk >> 16;
            acc += (float)weS[e * 64 + lane] * (float)hxrow[s * 64 + lane];
        }
        zS[r * 68 + lane] = acc;
    }
    __syncthreads();
    half8 zf0, zf1;
    {
        const float* zr = zS + lm * 68 + qd * 8;
        floatx4 va = *(const floatx4*)zr;
        floatx4 vb = *(const floatx4*)(zr + 4);
        floatx4 vc = *(const floatx4*)(zr + 32);
        floatx4 vd = *(const floatx4*)(zr + 36);
        #pragma unroll
        for (int ii = 0; ii < 4; ++ii) {
            zf0[ii] = (_Float16)va[ii]; zf0[4 + ii] = (_Float16)vb[ii];
            zf1[ii] = (_Float16)vc[ii]; zf1[4 + ii] = (_Float16)vd[ii];
        }
    }
    const half8* G = GWF + (size_t)(L * 3 + J) * 1024;
    #pragma unroll
    for (int u = 0; u < 2; ++u) {
        int t2 = wv * 2 + u;
        eacc[u] = __builtin_amdgcn_mfma_f32_16x16x32_f16(zf0, G[t2 * 128 + lane],      eacc[u], 0, 0, 0);
        eacc[u] = __builtin_amdgcn_mfma_f32_16x16x32_f16(zf1, G[t2 * 128 + 64 + lane], eacc[u], 0, 0, 0);
    }
    __syncthreads();   // zS+weS reusable by next class
}

// ================= fully-fused per-b kernel: 3 layers, zero HBM intermediates ==========
__global__ __launch_bounds__(256, 4)
void fused_kernel(const void* __restrict__ rs, const void* __restrict__ coords,
                  const int* __restrict__ same_s, const int* __restrict__ same_r,
                  const int* __restrict__ anti_s, const int* __restrict__ anti_r,
                  const int* __restrict__ ne_s,   const int* __restrict__ ne_r,
                  const char* __restrict__ wsB, void* __restrict__ out)
{
    const int b = blockIdx.x;
    const int tid = threadIdx.x;
    const int wv = tid >> 6, lane = tid & 63;
    const int qd = lane >> 4, lm = lane & 15;
    const int f32 = *(const int*)(wsB + OFF_FLAG_B);

    __shared__ __align__(16) _Float16 weS[128 * 64];   // one class's we (<=128 edges)
    __shared__ __align__(16) _Float16 hidA[4][1024];   // per-wave MLP scratch
    __shared__ float zS[16 * 68];
    __shared__ _Float16 hxS[2 * 1024];
    __shared__ _Float16 nucS[256];
    __shared__ __align__(16) _Float16 elecB[16 * 136];
    __shared__ int rlS[384];
    // total LDS = 16384+8192+4352+4096+512+4352+1536 = 39424 B -> 4 blocks/CU

    const _Float16* H0F = (const _Float16*)(wsB + OFF_H0_B);
    const _Float16* YWF = (const _Float16*)(wsB + OFF_YW_B);
    const float*    XT  = (const float*)(wsB + OFF_XT_B);
    const half8*    GWF = (const half8*)(wsB + OFF_GW_B);
    const half8*    HWF = (const half8*)(wsB + OFF_HW_B);

    for (int i = tid; i < 384; i += 256) rlS[i] = ((const int*)(wsB + OFF_RL_B))[i];
    for (int i = tid; i < 2048; i += 256) hxS[i] = H0F[((i >> 10) << 6) + (i & 63)];
    if (tid < 256) nucS[tid] = YWF[tid];

    _Float16* hid = hidA[wv];
    {   // zero once: cols 48..63 must stay 0 for the W2 MFMA A-operand
        half8 z8 = {0,0,0,0,0,0,0,0};
        *(half8*)(hid + lane * 8) = z8;
        *(half8*)(hid + 512 + lane * 8) = z8;
    }

    // per-lane featurization constants (channels qd*8+ii)
    float A0[8], B0[8], C0[8];
    #pragma unroll
    for (int ii = 0; ii < 8; ++ii) {
        float qf = (float)(qd * 8 + ii) * (1.f / 31.f);
        float mu = 10.f * qf * qf;
        float u = 7.f * __builtin_amdgcn_rcpf(1.f + 10.f * qf);  // 1/sigma
        float is2 = u * u;
        A0[ii] = -is2;
        B0[ii] = 2.f * mu * is2 - 1.f;
        C0[ii] = -(mu * mu) * is2;
    }

    // distances + features ONCE (layer-invariant). wave wv owns tiles:
    // same {wv, wv+4<7}, anti {wv, wv+4}, ne {wv}
    half8 fa_s0 = feat_tile(rs, coords, b, lm, f32, wv,     0, same_s, same_r, A0, B0, C0);
    half8 fa_s1 = {0,0,0,0,0,0,0,0};
    if (wv < 3)
          fa_s1 = feat_tile(rs, coords, b, lm, f32, wv + 4, 0, same_s, same_r, A0, B0, C0);
    half8 fa_a0 = feat_tile(rs, coords, b, lm, f32, wv,     1, anti_s, anti_r, A0, B0, C0);
    half8 fa_a1 = feat_tile(rs, coords, b, lm, f32, wv + 4, 1, anti_s, anti_r, A0, B0, C0);
    half8 fa_n  = feat_tile(rs, coords, b, lm, f32, wv,     2, ne_s,   ne_r,   A0, B0, C0);

    // elec accumulator lives in registers across all 3 layers
    floatx4 eacc[2];
    #pragma unroll
    for (int u = 0; u < 2; ++u) {
        float xv = XT[(wv * 2 + u) * 16 + lm];
        eacc[u][0] = xv; eacc[u][1] = xv; eacc[u][2] = xv; eacc[u][3] = xv;
    }
    __syncthreads();

    for (int L = 0; L < 3; ++L) {
        const int lj0 = L * 3;
        // ---- class 0: same-spin (7 tiles, 112 edges) ----
        we_tile(fa_s0, lj0 + 0, wv, wsB, hid, weS, lane, qd, lm);
        if (wv < 3) we_tile(fa_s1, lj0 + 0, wv + 4, wsB, hid, weS, lane, qd, lm);
        __syncthreads();
        scatter_zf_gmm<0, 7>(L, wv, lane, qd, lm, weS, hxS, rlS, zS, GWF, eacc);
        // ---- class 1: anti-spin (8 tiles, 128 edges) ----
        we_tile(fa_a0, lj0 + 1, wv,     wsB, hid, weS, lane, qd, lm);
        we_tile(fa_a1, lj0 + 1, wv + 4, wsB, hid, weS, lane, qd, lm);
        __syncthreads();
        scatter_zf_gmm<1, 8>(L, wv, lane, qd, lm, weS, hxS + 1024, rlS, zS, GWF, eacc);
        // ---- class 2: nuclear (4 tiles, 64 edges) ----
        we_tile(fa_n, lj0 + 2, wv, wsB, hid, weS, lane, qd, lm);
        __syncthreads();
        scatter_zf_gmm<2, 4>(L, wv, lane, qd, lm, weS, nucS, rlS, zS, GWF, eacc);

        if (L < 2) {
            // elec -> LDS (f16) -> hx for next layer (stays in LDS)
            #pragma unroll
            for (int u = 0; u < 2; ++u) {
                int t2 = wv * 2 + u;
                #pragma unroll
                for (int r = 0; r < 4; ++r)
                    elecB[(qd * 4 + r) * 136 + t2 * 16 + lm] = (_Float16)eacc[u][r];
            }
            __syncthreads();
            half8 ae[4];
            #pragma unroll
            for (int kt = 0; kt < 4; ++kt)
                ae[kt] = *(const half8*)(elecB + lm * 136 + kt * 32 + qd * 8);
            #pragma unroll
            for (int u = 0; u < 2; ++u) {
                int idx = wv * 2 + u;
                int j = idx >> 2, nt = idx & 3;
                floatx4 acc = {0.f,0.f,0.f,0.f};
                #pragma unroll
                for (int kt = 0; kt < 4; ++kt) {
                    half8 g = HWF[(size_t)(((L * 2 + j) * 4 + nt) * 4 + kt) * 64 + lane];
                    acc = __builtin_amdgcn_mfma_f32_16x16x32_f16(ae[kt], g, acc, 0, 0, 0);
                }
                #pragma unroll
                for (int r = 0; r < 4; ++r)
                    hxS[j * 1024 + (qd * 4 + r) * 64 + nt * 16 + lm] = (_Float16)acc[r];
            }
            // no barrier needed here: next hxS read is after next layer's
            // post-we_tile barrier; elecB rewritten only after next L's barriers
        }
    }

    if (f32) {
        float* o = (float*)out + (size_t)b * 2048;
        #pragma unroll
        for (int u = 0; u < 2; ++u)
            #pragma unroll
            for (int r = 0; r < 4; ++r)
                o[(qd * 4 + r) * 128 + (wv * 2 + u) * 16 + lm] = eacc[u][r];
    } else {
        __hip_bfloat16* o = (__hip_bfloat16*)out + (size_t)b * 2048;
        #pragma unroll
        for (int u = 0; u < 2; ++u)
            #pragma unroll
            for (int r = 0; r < 4; ++r)
                o[(qd * 4 + r) * 128 + (wv * 2 + u) * 16 + lm] = __float2bfloat16(eacc[u][r]);
    }
}

extern "C" void kernel_launch(void* const* d_in, const int* in_sizes, int n_in,
                              void* d_out, int out_size, void* d_ws, size_t ws_size,
                              hipStream_t stream) {
    const void* rs     = d_in[0];
    const void* coords = d_in[1];
    const void* X_tab  = d_in[2];
    const void* Y_w    = d_in[3];
    const void* wW1    = d_in[4];
    const void* wb1    = d_in[5];
    const void* wW2    = d_in[6];
    const void* h0     = d_in[7];
    const void* hW     = d_in[8];
    const void* gW     = d_in[9];
    const int* same_s = (const int*)d_in[10];
    const int* same_r = (const int*)d_in[11];
    const int* anti_s = (const int*)d_in[12];
    const int* anti_r = (const int*)d_in[13];
    const int* ne_s   = (const int*)d_in[14];
    const int* ne_r   = (const int*)d_in[15];
    char* wsB = (char*)d_ws;

    const int Bn = in_sizes[0] / (NE * 3);

    detect_kernel<<<1, 256, 0, stream>>>((const unsigned short*)rs, wsB);
    prep_kernel<<<288, 256, 0, stream>>>(wW1, wb1, wW2, h0, hW, gW, Y_w, X_tab, wsB);
    rlbuild_kernel<<<1, 64, 0, stream>>>(same_s, same_r, anti_s, anti_r, ne_s, ne_r, wsB);
    fused_kernel<<<Bn, 256, 0, stream>>>(rs, coords, same_s, same_r, anti_s, anti_r,
                                         ne_s, ne_r, wsB, d_out);
}